// Round 10
// baseline (301.311 us; speedup 1.0000x reference)
//
#include <hip/hip_runtime.h>
#include <cstdint>

typedef float floatx4 __attribute__((ext_vector_type(4)));
typedef _Float16 half8 __attribute__((ext_vector_type(8)));
typedef _Float16 half4v __attribute__((ext_vector_type(4)));

#define D_DIM 256
#define HW 1024
#define K_CODES 1024
#define NPIX 32768          // B*H*W
#define NELEM 8388608       // B*D*H*W

// output layout (floats): [quantized 8388608][q_loss][e_loss][vq_loss][idx 32768]
#define OFF_QLOSS 8388608
#define OFF_ELOSS 8388609
#define OFF_VQ    8388610
#define OFF_IDX   8388611

// ws layout (bytes) — total ~1.02 MB (< 1.18 MB proven in rounds 1/2)
#define WS_C2      0         // float * 1024 = 4096
#define WS_C2P     4096      // float * 1024 = 4096 (c2 + 1, biased-positive scores)
#define WS_DONE    8192      // int (last-block ticket)
#define WS_PART    8256      // double * 1024 = 8192
#define WS_PK4     16448     // uint4 * 32768 = 524288 (packed top-4 per pixel)
#define WS_CBS     540736    // swizzled fp16 codebook = 524288

// flag margin on UNPACKED packed scores: true-gap window 2.5e-4 (r4/r7-proven)
// + 2x packing quantization 2.4e-4  ->  5e-4 (r5-validated with packing)
#define MARGIN 5.0e-4f

// ---- numpy pairwise sum emulation for sum(v*v) over 256 elements ----
__device__ __forceinline__ float np_pairwise_sq_256(const float* __restrict__ a, int stride) {
    float half[2];
#pragma unroll
    for (int h = 0; h < 2; ++h) {
        const float* p = a + (size_t)(h * 128) * stride;
        float r[8];
#pragma unroll
        for (int j = 0; j < 8; ++j) { float t = p[(size_t)j * stride]; r[j] = __fmul_rn(t, t); }
        for (int i = 8; i < 128; i += 8)
#pragma unroll
            for (int j = 0; j < 8; ++j) {
                float t = p[(size_t)(i + j) * stride];
                r[j] = __fadd_rn(r[j], __fmul_rn(t, t));
            }
        half[h] = __fadd_rn(__fadd_rn(__fadd_rn(r[0], r[1]), __fadd_rn(r[2], r[3])),
                            __fadd_rn(__fadd_rn(r[4], r[5]), __fadd_rn(r[6], r[7])));
    }
    return __fadd_rn(half[0], half[1]);
}

// ---------------- kernel 0: prep ----------------
// blocks 0..255: swizzle codebook into MFMA-fragment order (scaled x1024).
// blocks 256..259: c2 (numpy-pairwise exact) + c2p = c2+1; zero the ticket.
__global__ __launch_bounds__(256) void prep_kernel(const float* __restrict__ cb,
                                                   _Float16* __restrict__ cbs,
                                                   float* __restrict__ c2,
                                                   float* __restrict__ c2p,
                                                   int* __restrict__ done) {
    int b = blockIdx.x;
    if (b < 256) {
        int idx = b * 256 + threadIdx.x;   // (code, d-quad)
        int c = idx >> 6;
        int d = (idx & 63) * 4;
        int s = d >> 5, q = (d >> 3) & 3, j0 = d & 7;
        int half = c >> 9, ch = (c >> 4) & 31, l15 = c & 15;
        int lane = q * 16 + l15;
        size_t o = ((((size_t)(half * 32 + ch) * 8 + s) * 64 + lane) * 8 + j0);
        floatx4 v = *(const floatx4*)(cb + (size_t)c * D_DIM + d);
        half4v h;
#pragma unroll
        for (int j = 0; j < 4; ++j) h[j] = (_Float16)(v[j] * 1024.0f);  // exact pow2
        *(half4v*)(cbs + o) = h;
    } else {
        if (b == 256 && threadIdx.x == 0) *done = 0;
        int k = (b - 256) * 256 + threadIdx.x;
        float v = np_pairwise_sq_256(cb + (size_t)k * D_DIM, 1);
        c2[k] = v;
        c2p[k] = __fadd_rn(v, 1.0f);
    }
}

// top-4 insert (floats; ties land inside MARGIN and are resolved by rescore)
__device__ __forceinline__ void ins4v(float v, int k, float* S, int* I) {
    if (v < S[3]) {
        S[3] = v; I[3] = k;
#pragma unroll
        for (int j = 3; j > 0; --j) {
            if (S[j] < S[j - 1]) {
                float ts = S[j]; S[j] = S[j - 1]; S[j - 1] = ts;
                int   ti = I[j]; I[j] = I[j - 1]; I[j - 1] = ti;
            }
        }
    }
}

// ---------------- kernel 1: MFMA stream GEMM -> packed top-4 ----------------
// ROUND-7-VERBATIM hot loop (44.6 us, VGPR=100, no spill): wave = 32 px x 512
// codes, B[2] double-buffer (B[4] spilled ~90B/thread -> 61 us, r9). Scores are
// biased positive (c2p = c2+1, constant shift) so the epilogue can pack
// (score_hi22 | code10) into one u32; t<64 writes uint4 pk4[px]. No atomics.
__global__ __launch_bounds__(256, 2) void gemm_swz(
        const float* __restrict__ x, const _Float16* __restrict__ cbs,
        const float* __restrict__ c2p, uint4* __restrict__ pk4) {
    __shared__ float scr[4][32 * 65];   // SoA [m1|i1|m2|i2][part][px pad65] = 33 KB

    const int t = threadIdx.x;
    const int w = t >> 6;
    const int l = t & 63;
    const int l15 = l & 15;
    const int q = l >> 4;
    const int pxg = w >> 1;          // pixel group 0/1 (32 px each)
    const int half = w & 1;          // code half 0/1 (512 codes each)
    const int px0 = blockIdx.x * 64;
    const int bimg = px0 >> 10;      // 64-px blocks never straddle images
    const int hwb = (px0 & 1023) + pxg * 32;
    const float* xb = x + (size_t)bimg * (D_DIM * HW);

    // ---- load A: 32 px x 256 d from fp32 NCHW, convert to f16 frags in regs ----
    half8 A[2][8];
#pragma unroll
    for (int r = 0; r < 2; ++r) {
        float tmp[64];
#pragma unroll
        for (int s = 0; s < 8; ++s)
#pragma unroll
            for (int j = 0; j < 8; ++j)
                tmp[s * 8 + j] = xb[(size_t)(s * 32 + q * 8 + j) * HW + hwb + r * 16 + l15];
#pragma unroll
        for (int s = 0; s < 8; ++s) {
            half8 h;
#pragma unroll
            for (int j = 0; j < 8; ++j) h[j] = (_Float16)tmp[s * 8 + j];
            A[r][s] = h;
        }
    }

    // ---- stream codes from fragment-ordered buffer: contiguous lane*16B loads ----
    const _Float16* base = cbs + (size_t)half * 131072;   // half block: 32*8*64*8 halves
    half8 B[2][8];
#pragma unroll
    for (int s = 0; s < 8; ++s)
        B[0][s] = *(const half8*)(base + (size_t)s * 512 + l * 8);
    float c2cur = c2p[half * 512 + l15];

    float m1[2][4], m2[2][4]; int i1[2][4], i2[2][4];
#pragma unroll
    for (int r = 0; r < 2; ++r)
#pragma unroll
        for (int a = 0; a < 4; ++a) {
            m1[r][a] = INFINITY; m2[r][a] = INFINITY; i1[r][a] = 0; i2[r][a] = 0;
        }

#pragma unroll 4
    for (int ch = 0; ch < 32; ++ch) {
        const int cur = ch & 1, nxt = cur ^ 1;
        float c2n = 0.f;
        if (ch < 31) {   // prefetch next chunk while computing this one
            const _Float16* nb = base + (size_t)(ch + 1) * 4096;   // 8*512 halves
#pragma unroll
            for (int s = 0; s < 8; ++s)
                B[nxt][s] = *(const half8*)(nb + (size_t)s * 512 + l * 8);
            c2n = c2p[half * 512 + (ch + 1) * 16 + l15];
        }
        // 4 independent MFMA chains (2 row-tiles x 2 K-halves)
        floatx4 ac[2][2];
#pragma unroll
        for (int r = 0; r < 2; ++r)
#pragma unroll
            for (int h = 0; h < 2; ++h) ac[r][h] = floatx4{0.f, 0.f, 0.f, 0.f};
#pragma unroll
        for (int s = 0; s < 4; ++s) {
            ac[0][0] = __builtin_amdgcn_mfma_f32_16x16x32_f16(A[0][s],     B[cur][s],     ac[0][0], 0, 0, 0);
            ac[1][0] = __builtin_amdgcn_mfma_f32_16x16x32_f16(A[1][s],     B[cur][s],     ac[1][0], 0, 0, 0);
            ac[0][1] = __builtin_amdgcn_mfma_f32_16x16x32_f16(A[0][s + 4], B[cur][s + 4], ac[0][1], 0, 0, 0);
            ac[1][1] = __builtin_amdgcn_mfma_f32_16x16x32_f16(A[1][s + 4], B[cur][s + 4], ac[1][1], 0, 0, 0);
        }
        const int code = half * 512 + ch * 16 + l15;
#pragma unroll
        for (int r = 0; r < 2; ++r)
#pragma unroll
            for (int a = 0; a < 4; ++a) {
                float dot = ac[r][0][a] + ac[r][1][a];
                float s = fmaf(-0.001953125f, dot, c2cur);   // (1+c2) - 2*dot, positive
                if (s < m1[r][a]) { m2[r][a] = m1[r][a]; i2[r][a] = i1[r][a]; m1[r][a] = s; i1[r][a] = code; }
                else if (s < m2[r][a]) { m2[r][a] = s; i2[r][a] = code; }
            }
        c2cur = c2n;
    }

    // ---- merge 32 partial top-2s per px, emit packed top-4 ----
    const int part = half * 16 + l15;
#pragma unroll
    for (int r = 0; r < 2; ++r)
#pragma unroll
        for (int a = 0; a < 4; ++a) {
            int px = pxg * 32 + r * 16 + q * 4 + a;
            int o = part * 65 + px;
            scr[0][o] = m1[r][a];
            scr[1][o] = __int_as_float(i1[r][a]);
            scr[2][o] = m2[r][a];
            scr[3][o] = __int_as_float(i2[r][a]);
        }
    __syncthreads();
    if (t < 64) {
        float S[4] = {INFINITY, INFINITY, INFINITY, INFINITY};
        int   I[4] = {0x7fffffff, 0x7fffffff, 0x7fffffff, 0x7fffffff};
        for (int p = 0; p < 32; ++p) {   // reads: stride 65 -> conflict-free
            int o = p * 65 + t;
            ins4v(scr[0][o], __float_as_int(scr[1][o]), S, I);
            ins4v(scr[2][o], __float_as_int(scr[3][o]), S, I);
        }
        uint4 pk;
        pk.x = (__float_as_uint(S[0]) & 0xFFFFFC00u) | (unsigned)I[0];
        pk.y = (__float_as_uint(S[1]) & 0xFFFFFC00u) | (unsigned)I[1];
        pk.z = (__float_as_uint(S[2]) & 0xFFFFFC00u) | (unsigned)I[2];
        pk.w = (__float_as_uint(S[3]) & 0xFFFFFC00u) | (unsigned)I[3];
        pk4[px0 + t] = pk;
    }
}

// ---------------- kernel 2: fused rescore + quantize + loss + finalize ----------
// 1024 blocks x 256 thr; block = 32 px. Phase A: unpack top-4, margin-test.
// Phase B: wave-per-flagged-pixel numpy-fp32 reference emulation -> final idx.
// Phase C: quantized write + f64 loss partial with the FINAL idx (no fixups).
// Last block (device ticket) folds partials into the three loss scalars.
__global__ __launch_bounds__(256) void quant_rescore(
        const float* __restrict__ x, const float* __restrict__ cb,
        const float* __restrict__ c2, const uint4* __restrict__ pk4,
        float* __restrict__ out_idx, float* __restrict__ out_q,
        double* __restrict__ partials, int* __restrict__ done,
        float* __restrict__ out) {
    __shared__ int sFinal[32];
    __shared__ int sCand[32][4];
    __shared__ int sNc[32];
    __shared__ int sList[32];
    __shared__ int sNum;
    __shared__ double sred[4];
    __shared__ bool amLast;

    const int t = threadIdx.x;
    const int px0 = blockIdx.x * 32;
    const int bimg = px0 >> 10;          // 32-px blocks never straddle images
    const float* xbase = x + (size_t)bimg * (D_DIM * HW);

    if (t == 0) sNum = 0;
    __syncthreads();

    // ---- phase A: unpack + flag ----
    if (t < 32) {
        uint4 pk = pk4[px0 + t];
        unsigned pu[4] = {pk.x, pk.y, pk.z, pk.w};
        float S0 = __uint_as_float(pu[0] & 0xFFFFFC00u);
        int nc = 1;
#pragma unroll
        for (int j = 1; j < 4; ++j) {
            float Sj = __uint_as_float(pu[j] & 0xFFFFFC00u);
            if (nc == j && Sj - S0 <= MARGIN) ++nc;
        }
        sFinal[t] = (int)(pu[0] & 1023u);
#pragma unroll
        for (int j = 0; j < 4; ++j) sCand[t][j] = (int)(pu[j] & 1023u);
        sNc[t] = nc;
        if (nc > 1) { int pos = atomicAdd(&sNum, 1); sList[pos] = t; }
    }
    __syncthreads();

    // ---- phase B: wave-per-flagged-pixel exact reference-fp32 emulation ----
    // ref (numpy fp32): d2_k = fl(fl(x2 - fl(2*mm_k)) + c2_k); argmin, first-idx ties.
    const int w = t >> 6, l = t & 63;
    const int nflag = sNum;
    for (int fi = w; fi < nflag; fi += 4) {
        const int pxl = sList[fi];
        const int nc = sNc[pxl];
        const int hw = (px0 & 1023) + pxl;
        const float* xcol = xbase + hw;

        // x2 with numpy's exact pairwise order: lanes 0..15 run the 8-acc chains
        float rj = 0.f;
        if (l < 16) {
            int h = l >> 3, j = l & 7;
            const float* p = xcol + (size_t)(h * 128) * HW;
            float v0 = p[(size_t)j * HW];
            rj = __fmul_rn(v0, v0);
            for (int ii = 1; ii < 16; ++ii) {
                float v = p[(size_t)(ii * 8 + j) * HW];
                rj = __fadd_rn(rj, __fmul_rn(v, v));
            }
        }
        float r0 = __shfl(rj, 0), r1 = __shfl(rj, 1), r2 = __shfl(rj, 2), r3 = __shfl(rj, 3);
        float r4 = __shfl(rj, 4), r5 = __shfl(rj, 5), r6 = __shfl(rj, 6), r7 = __shfl(rj, 7);
        float h0 = __fadd_rn(__fadd_rn(__fadd_rn(r0, r1), __fadd_rn(r2, r3)),
                             __fadd_rn(__fadd_rn(r4, r5), __fadd_rn(r6, r7)));
        r0 = __shfl(rj, 8); r1 = __shfl(rj, 9); r2 = __shfl(rj, 10); r3 = __shfl(rj, 11);
        r4 = __shfl(rj, 12); r5 = __shfl(rj, 13); r6 = __shfl(rj, 14); r7 = __shfl(rj, 15);
        float h1 = __fadd_rn(__fadd_rn(__fadd_rn(r0, r1), __fadd_rn(r2, r3)),
                             __fadd_rn(__fadd_rn(r4, r5), __fadd_rn(r6, r7)));
        float x2 = __fadd_rn(h0, h1);

        // f64 dots (stand-in for faithful sgemm); butterfly so all lanes agree
        float xv[4];
#pragma unroll
        for (int u = 0; u < 4; ++u) xv[u] = xcol[(size_t)(l + u * 64) * HW];
        float bd = INFINITY; int bi = 0x7fffffff;
        for (int jc = 0; jc < nc; ++jc) {
            int ckj = sCand[pxl][jc];
            const float* cr = cb + (size_t)ckj * D_DIM;
            double a = 0.0;
#pragma unroll
            for (int u = 0; u < 4; ++u) a += (double)xv[u] * (double)cr[l + u * 64];
#pragma unroll
            for (int off = 32; off > 0; off >>= 1) a += __shfl_xor(a, off);
            float mm = (float)a;
            float t1 = __fsub_rn(x2, __fmul_rn(2.0f, mm));
            float Dq = __fadd_rn(t1, c2[ckj]);
            if (Dq < bd || (Dq == bd && ckj < bi)) { bd = Dq; bi = ckj; }
        }
        if (l == 0) sFinal[pxl] = bi;
    }
    __syncthreads();

    // ---- phase C: quantized write + loss partial with final idx ----
    {
        const int pxl = t & 31;
        const int dg = t >> 5;           // 8 d-groups x 32 d
        const int P = px0 + pxl;
        const int hw = P & 1023;
        const int myidx = sFinal[pxl];
        if (t < 32) out_idx[P] = (float)myidx;
        const float* xcol = xbase + hw;
        float* qcol = out_q + (size_t)bimg * (D_DIM * HW) + hw;
        const floatx4* crow = (const floatx4*)(cb + (size_t)myidx * D_DIM) + dg * 8;
        float lsum = 0.f;
#pragma unroll
        for (int i = 0; i < 8; ++i) {
            floatx4 cv = crow[i];
            int dbase = dg * 32 + i * 4;
#pragma unroll
            for (int j = 0; j < 4; ++j) {
                size_t off = (size_t)(dbase + j) * HW;
                float xvv = xcol[off];
                qcol[off] = cv[j];               // coalesced across pxl lanes
                float df = cv[j] - xvv;
                lsum = fmaf(df, df, lsum);
            }
        }
        double ds = (double)lsum;
#pragma unroll
        for (int off = 32; off > 0; off >>= 1) ds += __shfl_down(ds, off);
        if ((t & 63) == 0) sred[t >> 6] = ds;
    }
    __syncthreads();
    if (t == 0) partials[blockIdx.x] = sred[0] + sred[1] + sred[2] + sred[3];

    // ---- last-block finalize (device-scope ticket) ----
    __threadfence();
    if (t == 0) amLast = (atomicAdd(done, 1) == (int)gridDim.x - 1);
    __syncthreads();
    if (amLast) {
        double s = 0.0;
        for (int i = t; i < 1024; i += 256) s += partials[i];
#pragma unroll
        for (int off = 32; off > 0; off >>= 1) s += __shfl_down(s, off);
        if ((t & 63) == 0) sred[t >> 6] = s;
        __syncthreads();
        if (t == 0) {
            double m = (sred[0] + sred[1] + sred[2] + sred[3]) / (double)NELEM;
            out[OFF_QLOSS] = (float)m;
            out[OFF_ELOSS] = (float)m;            // numerically identical to q_loss
            out[OFF_VQ]    = (float)(1.25 * m);   // q + 0.25*e
        }
    }
}

extern "C" void kernel_launch(void* const* d_in, const int* in_sizes, int n_in,
                              void* d_out, int out_size, void* d_ws, size_t ws_size,
                              hipStream_t stream) {
    const float* x  = (const float*)d_in[0];   // (32,256,32,32)
    const float* cb = (const float*)d_in[1];   // (1024,256)
    float* out = (float*)d_out;
    char* ws = (char*)d_ws;

    float*    c2      = (float*)(ws + WS_C2);
    float*    c2p     = (float*)(ws + WS_C2P);
    int*      done    = (int*)(ws + WS_DONE);
    double*   partials= (double*)(ws + WS_PART);
    uint4*    pk4     = (uint4*)(ws + WS_PK4);
    _Float16* cbs     = (_Float16*)(ws + WS_CBS);

    prep_kernel<<<260, 256, 0, stream>>>(cb, cbs, c2, c2p, done);
    gemm_swz<<<NPIX / 64, 256, 0, stream>>>(x, cbs, c2p, pk4);
    quant_rescore<<<NPIX / 32, 256, 0, stream>>>(x, cb, c2, pk4, out + OFF_IDX,
                                                 out, partials, done, out);
}